// Round 7
// baseline (53.850 us; speedup 1.0000x reference)
//
#include <hip/hip_runtime.h>
#include <hip/hip_bf16.h>
#include <stdint.h>

// Problem: out[N,OUT] = x[N,IN] @ weight[OUT,IN]^T + bias[OUT]
// N=4096, IN(K)=2048, OUT=2048, all fp32 in/out.
#define NROWS 4096
#define KDIM  2048
#define ODIM  2048
#define BM    256
#define BN    128
#define BK    64
#define NT    (KDIM / BK)   // 32 K-tiles
#define BMBK  (BM * BK)     // u16 elems per A buffer
#define BNBK  (BN * BK)

typedef __bf16 bf16x8 __attribute__((ext_vector_type(8)));
typedef float  f32x4  __attribute__((ext_vector_type(4)));
typedef unsigned short u16;
typedef unsigned int   u32;

__device__ __forceinline__ u16 f32_to_bf16_rne(float f) {
  u32 u = __builtin_bit_cast(u32, f);
  u += 0x7FFFu + ((u >> 16) & 1u);
  return (u16)(u >> 16);
}

// fused fp32 -> bf16 conversion for BOTH x and w (grid-stride); HBM-roofline
__global__ void cvt_both_f32_to_bf16(const float* __restrict__ x,
                                     const float* __restrict__ w,
                                     u16* __restrict__ xb, u16* __restrict__ wb,
                                     int n4x, int n4w) {
  int i = blockIdx.x * blockDim.x + threadIdx.x;
  const int stride = gridDim.x * blockDim.x;
  const int total = n4x + n4w;
  for (; i < total; i += stride) {
    const float4* in;
    ushort4* out;
    int j;
    if (i < n4x) { in = (const float4*)x; out = (ushort4*)xb; j = i; }
    else         { in = (const float4*)w; out = (ushort4*)wb; j = i - n4x; }
    float4 v = in[j];
    ushort4 o;
    o.x = f32_to_bf16_rne(v.x);
    o.y = f32_to_bf16_rne(v.y);
    o.z = f32_to_bf16_rne(v.z);
    o.w = f32_to_bf16_rne(v.w);
    out[j] = o;
  }
}

// async global->LDS, 16B/lane; LDS dest is wave-uniform base (+lane*16 in HW)
__device__ __forceinline__ void async16(const u16* g, const u16* l) {
  __builtin_amdgcn_global_load_lds((const __attribute__((address_space(1))) u32*)g,
                                   (__attribute__((address_space(3))) u32*)l,
                                   16, 0, 0);
}

// BM=256 x BN=128, BK=64, 256 threads = 4 waves (2Mx2N), per-wave 128x64
// (8x4 frags of 16x16x32; reads/FLOP = 0.0234 vs 64x64's 0.03125 -> LDS
// read traffic 128->96 KB/tile). TRIPLE-buffered LDS (144 KB), depth-2
// prefetch, ONE vmcnt(12)+s_barrier per K-tile, stage issues (12/tile)
// interleaved 6+6 into the two kk-phases. T1 XCD swizzle, T2 LDS swizzle
// (inverse-swizzled global src + linear gload_lds dest, same XOR on reads),
// T5 setprio around MFMA clusters.
__global__ void __launch_bounds__(256, 1)
gemm_bt_bf16(const u16* __restrict__ A, const u16* __restrict__ B,
             const float* __restrict__ bias, float* __restrict__ C) {
  __shared__ __align__(16) u16 As[3 * BMBK];  // 96 KB
  __shared__ __align__(16) u16 Bs[3 * BNBK];  // 48 KB

  const int t    = threadIdx.x;
  const int lane = t & 63;
  const int wave = t >> 6;      // 0..3
  const int wrow = wave >> 1;   // 0..1 (M, x128)
  const int wcol = wave & 1;    // 0..1 (N, x64)
  const int fr   = lane & 15;
  const int fq   = lane >> 4;

  // T1 XCD swizzle: 256 blocks, 256%8==0 -> bijective simple form.
  const int bid  = blockIdx.x;
  const int swz  = (bid & 7) * 32 + (bid >> 3);
  const int brow = (swz >> 4) * BM;   // 16 row-panels
  const int bcol = (swz & 15) * BN;   // 16 col-panels

  // staging: 256 thr x 16B = 4 KB = 32 rows/issue. A: 8 issues, B: 4.
  const int srow = t >> 3;                          // 0..31
  const int scol = ((t & 7) ^ (srow & 7)) * 8;      // inverse-swizzled col
  const u16* pA = A + (size_t)(brow + srow) * KDIM + scol;
  const u16* pB = B + (size_t)(bcol + srow) * KDIM + scol;

  f32x4 acc[8][4] = {};

  const int xr   = fr & 7;            // read-side XOR (row&7 == fr&7)
  const int arow = wrow * 128 + fr;   // + m*16, m=0..7
  const int brf  = wcol * 64 + fr;    // + n*16, n=0..3

  // stage halves: H=0 -> A issues g=0..5; H=1 -> A g=6..7 + B g=0..3
#define STG_H0(buf, KOFF)                                                \
  do {                                                                   \
    u16* la = As + (buf) * BMBK + wave * 512;                            \
    async16(pA + (KOFF),                       la);                      \
    async16(pA + (size_t) 32 * KDIM + (KOFF),  la + 2048);               \
    async16(pA + (size_t) 64 * KDIM + (KOFF),  la + 4096);               \
    async16(pA + (size_t) 96 * KDIM + (KOFF),  la + 6144);               \
    async16(pA + (size_t)128 * KDIM + (KOFF),  la + 8192);               \
    async16(pA + (size_t)160 * KDIM + (KOFF),  la + 10240);              \
  } while (0)
#define STG_H1(buf, KOFF)                                                \
  do {                                                                   \
    u16* la = As + (buf) * BMBK + wave * 512;                            \
    u16* lb = Bs + (buf) * BNBK + wave * 512;                            \
    async16(pA + (size_t)192 * KDIM + (KOFF),  la + 12288);              \
    async16(pA + (size_t)224 * KDIM + (KOFF),  la + 14336);              \
    async16(pB + (KOFF),                       lb);                      \
    async16(pB + (size_t) 32 * KDIM + (KOFF),  lb + 2048);               \
    async16(pB + (size_t) 64 * KDIM + (KOFF),  lb + 4096);               \
    async16(pB + (size_t) 96 * KDIM + (KOFF),  lb + 6144);               \
  } while (0)

  // one K-tile: fence, then 2 kk-phases with stage halves interleaved
#define TILE(bi, DOSTG, KOFF, VMN)                                       \
  do {                                                                   \
    asm volatile("s_waitcnt vmcnt(" #VMN ")" ::: "memory");              \
    __builtin_amdgcn_s_barrier();                                        \
    __builtin_amdgcn_sched_barrier(0);                                   \
    const u16* ab = As + (bi) * BMBK;                                    \
    const u16* bb = Bs + (bi) * BNBK;                                    \
    bf16x8 af[8], bf[4];                                                 \
    { const int cg = ((0 * 4 + fq) ^ xr) * 8;                            \
      _Pragma("unroll")                                                  \
      for (int m = 0; m < 8; ++m)                                        \
        af[m] = *reinterpret_cast<const bf16x8*>(                        \
            ab + (arow + m * 16) * BK + cg);                             \
      _Pragma("unroll")                                                  \
      for (int n = 0; n < 4; ++n)                                        \
        bf[n] = *reinterpret_cast<const bf16x8*>(                        \
            bb + (brf + n * 16) * BK + cg); }                            \
    if (DOSTG) STG_H0((((bi) + 2) % 3), KOFF);                           \
    __builtin_amdgcn_s_setprio(1);                                       \
    _Pragma("unroll")                                                    \
    for (int m = 0; m < 8; ++m)                                          \
      _Pragma("unroll")                                                  \
      for (int n = 0; n < 4; ++n)                                        \
        acc[m][n] = __builtin_amdgcn_mfma_f32_16x16x32_bf16(             \
            af[m], bf[n], acc[m][n], 0, 0, 0);                           \
    __builtin_amdgcn_s_setprio(0);                                       \
    { const int cg = ((1 * 4 + fq) ^ xr) * 8;                            \
      _Pragma("unroll")                                                  \
      for (int m = 0; m < 8; ++m)                                        \
        af[m] = *reinterpret_cast<const bf16x8*>(                        \
            ab + (arow + m * 16) * BK + cg);                             \
      _Pragma("unroll")                                                  \
      for (int n = 0; n < 4; ++n)                                        \
        bf[n] = *reinterpret_cast<const bf16x8*>(                        \
            bb + (brf + n * 16) * BK + cg); }                            \
    if (DOSTG) STG_H1((((bi) + 2) % 3), KOFF);                           \
    __builtin_amdgcn_s_setprio(1);                                       \
    _Pragma("unroll")                                                    \
    for (int m = 0; m < 8; ++m)                                          \
      _Pragma("unroll")                                                  \
      for (int n = 0; n < 4; ++n)                                        \
        acc[m][n] = __builtin_amdgcn_mfma_f32_16x16x32_bf16(             \
            af[m], bf[n], acc[m][n], 0, 0, 0);                           \
    __builtin_amdgcn_s_setprio(0);                                       \
  } while (0)

  // prologue: stage tile 0 -> buf0, tile 1 -> buf1 (24 loads in flight)
  STG_H0(0, 0);        STG_H1(0, 0);
  STG_H0(1, BK);       STG_H1(1, BK);

  // main loop: 10 iters x 3 tiles = tiles 0..29; stages tiles 2..31
#pragma unroll 1
  for (int i = 0; i < NT / 3; ++i) {
    TILE(0, true, 2 * BK, 12);           // compute 3i+0, stage 3i+2 -> buf2
    TILE(1, true, 3 * BK, 12);           // compute 3i+1, stage 3i+3 -> buf0
    TILE(2, true, 4 * BK, 12);           // compute 3i+2, stage 3i+4 -> buf1
    pA += 3 * BK;
    pB += 3 * BK;
  }
  // epilogue: tiles 30 (buf0), 31 (buf1) — no staging
  TILE(0, false, 0, 12);
  TILE(1, false, 0, 0);

#undef TILE
#undef STG_H0
#undef STG_H1

  // ---- epilogue: C/D layout col=lane&15, row=(lane>>4)*4+reg ----
  float bv[4];
#pragma unroll
  for (int n = 0; n < 4; ++n)
    bv[n] = bias[bcol + wcol * 64 + n * 16 + fr];
#pragma unroll
  for (int m = 0; m < 8; ++m) {
    const int row0 = brow + wrow * 128 + m * 16 + fq * 4;
#pragma unroll
    for (int n = 0; n < 4; ++n) {
      const int col = bcol + wcol * 64 + n * 16 + fr;
      float* o = C + (size_t)row0 * ODIM + col;
#pragma unroll
      for (int j = 0; j < 4; ++j)
        o[(size_t)j * ODIM] = acc[m][n][j] + bv[n];
    }
  }
}

// correctness-only fallback if ws is too small (fp32, 16x16 LDS tiles)
__global__ void fallback_gemm(const float* __restrict__ x, const float* __restrict__ w,
                              const float* __restrict__ bias, float* __restrict__ out) {
  __shared__ float xs[16][17];
  __shared__ float wsm[16][17];
  const int tx = threadIdx.x & 15, ty = threadIdx.x >> 4;
  const int row = blockIdx.y * 16 + ty;
  const int colb = blockIdx.x * 16;
  float acc = 0.f;
  for (int k0 = 0; k0 < KDIM; k0 += 16) {
    xs[ty][tx]  = x[(size_t)row * KDIM + k0 + tx];
    wsm[ty][tx] = w[(size_t)(colb + ty) * KDIM + k0 + tx];
    __syncthreads();
#pragma unroll
    for (int kk = 0; kk < 16; ++kk)
      acc += xs[ty][kk] * wsm[tx][kk];
    __syncthreads();
  }
  out[(size_t)row * ODIM + colb + tx] = acc + bias[colb + tx];
}

extern "C" void kernel_launch(void* const* d_in, const int* in_sizes, int n_in,
                              void* d_out, int out_size, void* d_ws, size_t ws_size,
                              hipStream_t stream) {
  const float* x    = (const float*)d_in[0];
  const float* w    = (const float*)d_in[1];
  const float* bias = (const float*)d_in[2];
  float* out = (float*)d_out;

  const size_t needA = (size_t)NROWS * KDIM * sizeof(u16); // 16 MiB
  const size_t needB = (size_t)ODIM  * KDIM * sizeof(u16); //  8 MiB
  if (ws_size < needA + needB) {
    dim3 grid(ODIM / 16, NROWS / 16);
    fallback_gemm<<<grid, 256, 0, stream>>>(x, w, bias, out);
    return;
  }

  u16* xb = (u16*)d_ws;
  u16* wb = xb + (size_t)NROWS * KDIM;

  const int n4x = NROWS * KDIM / 4;  // 2M float4
  const int n4w = ODIM * KDIM / 4;   // 1M float4
  cvt_both_f32_to_bf16<<<2048, 256, 0, stream>>>(x, w, xb, wb, n4x, n4w);

  const int nblocks = (NROWS / BM) * (ODIM / BN);  // 16*16 = 256
  gemm_bt_bf16<<<nblocks, 256, 0, stream>>>(xb, wb, bias, out);
}